// Round 5
// baseline (1777.632 us; speedup 1.0000x reference)
//
#include <hip/hip_runtime.h>
#include <hip/hip_bf16.h>
#include <stdint.h>

#define N_NODES 16384
#define GG      128
#define HD      64
#define MAXD    192
#define BN_EPS  1e-5f

typedef unsigned short u16;
typedef unsigned int   u32;
typedef unsigned long long u64;

__device__ __forceinline__ float bf2f(u16 u) {
    union { u32 i; float f; } c; c.i = ((u32)u) << 16; return c.f;
}
// param load in native dtype (flag: 1=f32, 0=bf16)
__device__ __forceinline__ float ldp(const void* p, int i, int flag) {
    return flag ? ((const float*)p)[i] : bf2f(((const u16*)p)[i]);
}

// ---------------------------------------------------------------------------
// zero f64 stats (512) + per-row counters + probe input dtype from
// adj[0][0]==1.0: f32 -> word0 low16 == 0; bf16 -> low16 = 0x3F80 != 0.
__global__ __launch_bounds__(256) void k_init(
    const u32* __restrict__ adj32, double* __restrict__ statsD,
    int* __restrict__ cnt, int* __restrict__ flag)
{
    const int gid = blockIdx.x * 256 + threadIdx.x;
    if (gid < N_NODES) cnt[gid] = 0;
    if (gid < 512) statsD[gid] = 0.0;
    if (gid == 0) *flag = ((adj32[0] & 0xFFFFu) == 0) ? 1 : 0;
}

// ---------------------------------------------------------------------------
// Fully-parallel streaming scan of adj (1 GiB f32 / 0.5 GiB bf16).
// Each lane zero-tests one uint4; nonzero columns are appended (unordered)
// to cols[row] via a global atomic counter. No gathers here -> pure BW.
__global__ __launch_bounds__(256) void k_scan(
    const void* __restrict__ adjv, u16* __restrict__ cols,
    int* __restrict__ cnt, const int* __restrict__ flagp)
{
    const int flag = *flagp;
    const size_t stride = (size_t)gridDim.x * 256;
    size_t i = (size_t)blockIdx.x * 256 + threadIdx.x;
    if (flag) {  // f32: uint4 = 4 elements
        const uint4* __restrict__ a = (const uint4*)adjv;
        const size_t total = (size_t)N_NODES * N_NODES / 4;
        for (; i < total; i += stride) {
            uint4 w = a[i];
            if (w.x | w.y | w.z | w.w) {
                size_t base = i * 4;
                int row = (int)(base >> 14);
                int col = (int)(base & 16383);
                u16* crow = cols + (size_t)row * MAXD;
                if (w.x) { int p = atomicAdd(&cnt[row], 1); if (p < MAXD) crow[p] = (u16)(col);     }
                if (w.y) { int p = atomicAdd(&cnt[row], 1); if (p < MAXD) crow[p] = (u16)(col + 1); }
                if (w.z) { int p = atomicAdd(&cnt[row], 1); if (p < MAXD) crow[p] = (u16)(col + 2); }
                if (w.w) { int p = atomicAdd(&cnt[row], 1); if (p < MAXD) crow[p] = (u16)(col + 3); }
            }
        }
    } else {     // bf16: uint4 = 8 elements
        const uint4* __restrict__ a = (const uint4*)adjv;
        const size_t total = (size_t)N_NODES * N_NODES / 8;
        for (; i < total; i += stride) {
            uint4 w = a[i];
            if (w.x | w.y | w.z | w.w) {
                size_t base = i * 8;
                int row = (int)(base >> 14);
                int col = (int)(base & 16383);
                u16* crow = cols + (size_t)row * MAXD;
                const u32 h[4] = {w.x, w.y, w.z, w.w};
                #pragma unroll
                for (int e = 0; e < 8; ++e) {
                    if ((u16)(h[e >> 1] >> ((e & 1) * 16))) {
                        int p = atomicAdd(&cnt[row], 1);
                        if (p < MAXD) crow[p] = (u16)(col + e);
                    }
                }
            }
        }
    }
}

// ---------------------------------------------------------------------------
// pooled[i,:] = (1/deg_i) * sum_k x[cols[i,k],:]  — one wave per row, ILP-4.
// Also finalizes invdeg[i]. Runs after the adj stream, so x is L2-resident.
__global__ __launch_bounds__(256) void k_gather(
    const void* __restrict__ xv, const u16* __restrict__ cols,
    int* __restrict__ cnt, float* __restrict__ invdeg,
    float* __restrict__ pooled, const int* __restrict__ flagp)
{
    const int wave = threadIdx.x >> 6, lane = threadIdx.x & 63;
    const int row = blockIdx.x * 4 + wave;
    const int flag = *flagp;
    const u16* __restrict__ crow = cols + (size_t)row * MAXD;
    int n = cnt[row];
    if (n > MAXD) n = MAXD;
    float acc = 0.f;
    int k = 0;
    if (flag) {
        const float* __restrict__ x = (const float*)xv;
        for (; k + 4 <= n; k += 4) {
            ushort4 j4 = *(const ushort4*)&crow[k];
            float v0 = x[(size_t)j4.x * HD + lane];
            float v1 = x[(size_t)j4.y * HD + lane];
            float v2 = x[(size_t)j4.z * HD + lane];
            float v3 = x[(size_t)j4.w * HD + lane];
            acc += (v0 + v1) + (v2 + v3);
        }
        for (; k < n; ++k) acc += x[(size_t)crow[k] * HD + lane];
    } else {
        const u16* __restrict__ x = (const u16*)xv;
        for (; k + 4 <= n; k += 4) {
            ushort4 j4 = *(const ushort4*)&crow[k];
            float v0 = bf2f(x[(size_t)j4.x * HD + lane]);
            float v1 = bf2f(x[(size_t)j4.y * HD + lane]);
            float v2 = bf2f(x[(size_t)j4.z * HD + lane]);
            float v3 = bf2f(x[(size_t)j4.w * HD + lane]);
            acc += (v0 + v1) + (v2 + v3);
        }
        for (; k < n; ++k) acc += bf2f(x[(size_t)crow[k] * HD + lane]);
    }
    float inv = 1.f / (float)n;                     // n >= 1 (self-loop)
    pooled[(size_t)row * HD + lane] = acc * inv;
    if (lane == 0) { invdeg[row] = inv; if (cnt[row] > MAXD) cnt[row] = MAXD; }
}

// ---------------------------------------------------------------------------
// Plain GEMM: dst[N,64] = src[N,64] @ W[64,64] + bias.
__global__ __launch_bounds__(256) void k_mm(
    const float* __restrict__ src, const void* __restrict__ W,
    const void* __restrict__ bias, float* __restrict__ dst,
    const int* __restrict__ flagp)
{
    __shared__ float Wf[64 * 64];
    __shared__ float S[4 * 64];
    const int tid = threadIdx.x;
    const int flag = *flagp;
    for (int i = tid; i < 64 * 64; i += 256) Wf[i] = ldp(W, i, flag);
    const int rbase = blockIdx.x * 4;
    S[tid] = src[(size_t)rbase * 64 + tid];
    __syncthreads();
    const int f = tid & 63, r = tid >> 6;
    float acc = ldp(bias, f, flag);
    #pragma unroll
    for (int k = 0; k < 64; ++k)
        acc = fmaf(S[r * 64 + k], Wf[k * 64 + f], acc);
    dst[(size_t)(rbase + r) * 64 + f] = acc;
}

// ---------------------------------------------------------------------------
// Column stats in f64: statsOut[f] += sum, statsOut[64+f] += sumsq.
__global__ __launch_bounds__(256) void k_stats(
    const float* __restrict__ src, double* __restrict__ statsOut)
{
    __shared__ double shs[256];
    __shared__ double shq[256];
    const int tid = threadIdx.x;
    const int f = tid & 63, rsub = tid >> 6;
    const int rbase = blockIdx.x * 64;
    double s = 0.0, q = 0.0;
    for (int r = rsub; r < 64; r += 4) {
        float v = src[(size_t)(rbase + r) * 64 + f];
        s += (double)v;
        q += (double)v * (double)v;
    }
    shs[tid] = s; shq[tid] = q;
    __syncthreads();
    if (tid < 64) {
        double S = shs[tid] + shs[64 + tid] + shs[128 + tid] + shs[192 + tid];
        double Q = shq[tid] + shq[64 + tid] + shq[128 + tid] + shq[192 + tid];
        atomicAdd(&statsOut[tid], S);
        atomicAdd(&statsOut[64 + tid], Q);
    }
}

// ---------------------------------------------------------------------------
// dst = relu(A*src + C) with A,C from f64 stats + gamma/beta. All f32 I/O.
__global__ __launch_bounds__(256) void k_bnrelu(
    const float* __restrict__ src, const double* __restrict__ stats,
    const void* __restrict__ g, const void* __restrict__ be,
    float* __restrict__ dst, const int* __restrict__ flagp)
{
    __shared__ float ac[128];
    const int tid = threadIdx.x;
    const int flag = *flagp;
    if (tid < 64) {
        double m = stats[tid] * (1.0 / N_NODES);
        double v = stats[64 + tid] * (1.0 / N_NODES) - m * m;
        float A = ldp(g, tid, flag) / sqrtf((float)v + BN_EPS);
        ac[tid] = A;
        ac[64 + tid] = ldp(be, tid, flag) - (float)m * A;
    }
    __syncthreads();
    const size_t idx = ((size_t)blockIdx.x * 256 + tid) * 4;
    const int f0 = (int)(idx & 63);
    float4 t = *(const float4*)&src[idx];
    const float4 A4 = *(const float4*)&ac[f0];
    const float4 C4 = *(const float4*)&ac[64 + f0];
    float4 r;
    r.x = fmaxf(fmaf(A4.x, t.x, C4.x), 0.f);
    r.y = fmaxf(fmaf(A4.y, t.y, C4.y), 0.f);
    r.z = fmaxf(fmaf(A4.z, t.z, C4.z), 0.f);
    r.w = fmaxf(fmaf(A4.w, t.w, C4.w), 0.f);
    *(float4*)&dst[idx] = r;
}

// ---------------------------------------------------------------------------
// pooled[i,:] = invdeg[i] * sum_k h[cols[i,k],:]  (ILP-4 gather)
__global__ __launch_bounds__(256) void k_spmm(
    const float* __restrict__ h, const u16* __restrict__ cols,
    const int* __restrict__ cnt, const float* __restrict__ invdeg,
    float* __restrict__ pooled)
{
    const int wave = threadIdx.x >> 6, lane = threadIdx.x & 63;
    const int row = blockIdx.x * 4 + wave;
    const u16* __restrict__ crow = cols + (size_t)row * MAXD;
    const int n = cnt[row];
    float acc = 0.f;
    int k = 0;
    for (; k + 4 <= n; k += 4) {
        ushort4 j4 = *(const ushort4*)&crow[k];
        float v0 = h[(size_t)j4.x * HD + lane];
        float v1 = h[(size_t)j4.y * HD + lane];
        float v2 = h[(size_t)j4.z * HD + lane];
        float v3 = h[(size_t)j4.w * HD + lane];
        acc += (v0 + v1) + (v2 + v3);
    }
    for (; k < n; ++k) acc += h[(size_t)crow[k] * HD + lane];
    pooled[(size_t)row * HD + lane] = acc * invdeg[row];
}

// ---------------------------------------------------------------------------
// out[g,:] = sum_j gp[g,j] * h[j,:]; zero weights skipped (wave-uniform test)
__global__ __launch_bounds__(1024) void k_pool(
    const void* __restrict__ gpv, const float* __restrict__ h,
    float* __restrict__ out, const int* __restrict__ flagp)
{
    __shared__ float red[16 * 64];
    const int g = blockIdx.x;
    const int wave = threadIdx.x >> 6, lane = threadIdx.x & 63;
    const int flag = *flagp;
    float acc = 0.f;
    const int jb0 = wave * (N_NODES / 16);
    if (flag) {
        const float* __restrict__ grow = (const float*)gpv + (size_t)g * N_NODES;
        for (int jb = jb0; jb < jb0 + N_NODES / 16; jb += 4) {
            float4 raw = *(const float4*)(grow + jb);
            if (raw.x != 0.f) acc += raw.x * h[(size_t)(jb + 0) * HD + lane];
            if (raw.y != 0.f) acc += raw.y * h[(size_t)(jb + 1) * HD + lane];
            if (raw.z != 0.f) acc += raw.z * h[(size_t)(jb + 2) * HD + lane];
            if (raw.w != 0.f) acc += raw.w * h[(size_t)(jb + 3) * HD + lane];
        }
    } else {
        const u16* __restrict__ grow = (const u16*)gpv + (size_t)g * N_NODES;
        for (int jb = jb0; jb < jb0 + N_NODES / 16; jb += 8) {
            uint4 raw = *(const uint4*)(grow + jb);
            const u32 w[4] = {raw.x, raw.y, raw.z, raw.w};
            #pragma unroll
            for (int e = 0; e < 8; ++e) {
                u16 u = (u16)(w[e >> 1] >> ((e & 1) * 16));
                if (u) acc += bf2f(u) * h[(size_t)(jb + e) * HD + lane];
            }
        }
    }
    red[wave * 64 + lane] = acc;
    __syncthreads();
    if (wave == 0) {
        float s = 0.f;
        #pragma unroll
        for (int w2 = 0; w2 < 16; ++w2) s += red[w2 * 64 + lane];
        out[g * 64 + lane] = s;
    }
}

// ---------------------------------------------------------------------------
extern "C" void kernel_launch(void* const* d_in, const int* in_sizes, int n_in,
                              void* d_out, int out_size, void* d_ws, size_t ws_size,
                              hipStream_t stream)
{
    const void* x    = d_in[0];
    const void* adj  = d_in[1];
    const void* gp   = d_in[2];
    const void* W1_0 = d_in[3];
    const void* b1_0 = d_in[4];
    const void* g1_0 = d_in[5];
    const void* be1_0= d_in[6];
    const void* W2_0 = d_in[7];
    const void* b2_0 = d_in[8];
    const void* g_0  = d_in[9];
    const void* be_0 = d_in[10];
    const void* W1_1 = d_in[11];
    const void* b1_1 = d_in[12];
    const void* g1_1 = d_in[13];
    const void* be1_1= d_in[14];
    const void* W2_1 = d_in[15];
    const void* b2_1 = d_in[16];
    const void* g_1  = d_in[17];
    const void* be_1 = d_in[18];

    char* ws = (char*)d_ws;
    float*  P      = (float*) (ws);                        // 4 MB
    float*  A      = (float*) (ws + (4u  << 20));          // 4 MB
    float*  B      = (float*) (ws + (8u  << 20));          // 4 MB
    u16*    cols   = (u16*)   (ws + (12u << 20));          // 6 MB
    int*    cnt    = (int*)   (ws + (18u << 20));          // 64 KB
    float*  invdeg = (float*) (ws + (18u << 20) + 65536);  // 64 KB
    double* sd     = (double*)(ws + (18u << 20) + 131072); // 512 f64 = 4 KB
    int*    flag   = (int*)   (ws + (18u << 20) + 131072 + 4096);

    // Outputs are float32 (reference output dtype). Output 1 (h_nodes) is
    // written in-place by the final k_bnrelu; k_pool reads it from d_out.
    float* out_pool  = (float*)d_out;            // [128,64]
    float* out_nodes = (float*)d_out + GG * HD;  // [16384,64]

    const int EB = (N_NODES * HD / 4) / 256;  // elementwise grid (1024)

    k_init<<<N_NODES / 256, 256, 0, stream>>>((const u32*)adj, sd, cnt, flag);
    k_scan<<<16384, 256, 0, stream>>>(adj, cols, cnt, flag);
    k_gather<<<N_NODES / 4, 256, 0, stream>>>(x, cols, cnt, invdeg, P, flag);

    // ----- layer 0 -----
    k_mm<<<N_NODES / 4, 256, 0, stream>>>(P, W1_0, b1_0, A, flag);
    k_stats<<<256, 256, 0, stream>>>(A, sd + 0);
    k_bnrelu<<<EB, 256, 0, stream>>>(A, sd + 0, g1_0, be1_0, B, flag);
    k_mm<<<N_NODES / 4, 256, 0, stream>>>(B, W2_0, b2_0, P, flag);
    k_stats<<<256, 256, 0, stream>>>(P, sd + 128);
    k_bnrelu<<<EB, 256, 0, stream>>>(P, sd + 128, g_0, be_0, A, flag);   // h0
    k_spmm<<<N_NODES / 4, 256, 0, stream>>>(A, cols, cnt, invdeg, B);    // pooled1
    // ----- layer 1 -----
    k_mm<<<N_NODES / 4, 256, 0, stream>>>(B, W1_1, b1_1, P, flag);
    k_stats<<<256, 256, 0, stream>>>(P, sd + 256);
    k_bnrelu<<<EB, 256, 0, stream>>>(P, sd + 256, g1_1, be1_1, A, flag);
    k_mm<<<N_NODES / 4, 256, 0, stream>>>(A, W2_1, b2_1, B, flag);
    k_stats<<<256, 256, 0, stream>>>(B, sd + 384);
    k_bnrelu<<<EB, 256, 0, stream>>>(B, sd + 384, g_1, be_1, out_nodes, flag); // h1 -> output 1
    k_pool<<<GG, 1024, 0, stream>>>(gp, out_nodes, out_pool, flag);            // output 0
}

// Round 6
// 1672.412 us; speedup vs baseline: 1.0629x; 1.0629x over previous
//
#include <hip/hip_runtime.h>
#include <hip/hip_bf16.h>
#include <stdint.h>

#define N_NODES 16384
#define GG      128
#define HD      64
#define MAXD    192
#define BN_EPS  1e-5f

typedef unsigned short u16;
typedef unsigned int   u32;
typedef unsigned long long u64;

__device__ __forceinline__ float bf2f(u16 u) {
    union { u32 i; float f; } c; c.i = ((u32)u) << 16; return c.f;
}
// param load in native dtype (flag: 1=f32, 0=bf16)
__device__ __forceinline__ float ldp(const void* p, int i, int flag) {
    return flag ? ((const float*)p)[i] : bf2f(((const u16*)p)[i]);
}

// ---------------------------------------------------------------------------
// zero f64 stats (512) + probe input dtype from adj[0][0]==1.0:
// f32 -> word0 low16 == 0; bf16 -> low16 = 0x3F80 != 0.
__global__ __launch_bounds__(256) void k_init(
    const u32* __restrict__ adj32, double* __restrict__ statsD,
    int* __restrict__ flag)
{
    const int gid = blockIdx.x * 256 + threadIdx.x;
    if (gid < 512) statsD[gid] = 0.0;
    if (gid == 0) *flag = ((adj32[0] & 0xFFFFu) == 0) ? 1 : 0;
}

// ---------------------------------------------------------------------------
// Streaming CSR build, NO ATOMICS: one wave per row. Each lane zero-tests a
// uint4; nonzero columns are compacted with ballot + popcount-prefix (base is
// wave-uniform). Row-contiguous streaming keeps DRAM locality; ~25 VALU
// instrs per 1 KiB chunk -> memory-bound.
__global__ __launch_bounds__(256) void k_scan(
    const void* __restrict__ adjv, u16* __restrict__ cols,
    int* __restrict__ cnt, const int* __restrict__ flagp)
{
    const int wave = threadIdx.x >> 6, lane = threadIdx.x & 63;
    const int row = blockIdx.x * 4 + wave;
    u16* __restrict__ crow = cols + (size_t)row * MAXD;
    const int flag = *flagp;
    const u64 ltmask = ((1ull << lane) - 1ull);   // lanes below me (lane 63 ok)

    int base = 0;
    if (flag) {  // ---- f32: uint4 = 4 elements ----
        const u32* __restrict__ arow = (const u32*)adjv + (size_t)row * N_NODES;
        uint4 nxt = *(const uint4*)(arow + lane * 4);
        for (int c = 0; c < N_NODES; c += 256) {
            uint4 raw = nxt;
            if (c + 256 < N_NODES)
                nxt = *(const uint4*)(arow + c + 256 + lane * 4);
            const u32 w[4] = {raw.x, raw.y, raw.z, raw.w};
            #pragma unroll
            for (int e = 0; e < 4; ++e) {
                u64 m = __ballot(w[e] != 0);
                if (m) {
                    if (w[e]) {
                        int p = base + __popcll(m & ltmask);
                        if (p < MAXD) crow[p] = (u16)(c + lane * 4 + e);
                    }
                    base += __popcll(m);
                }
            }
        }
    } else {     // ---- bf16: uint4 = 8 elements ----
        const u16* __restrict__ arow = (const u16*)adjv + (size_t)row * N_NODES;
        uint4 nxt = *(const uint4*)(arow + lane * 8);
        for (int c = 0; c < N_NODES; c += 512) {
            uint4 raw = nxt;
            if (c + 512 < N_NODES)
                nxt = *(const uint4*)(arow + c + 512 + lane * 8);
            const u32 h[4] = {raw.x, raw.y, raw.z, raw.w};
            #pragma unroll
            for (int e = 0; e < 8; ++e) {
                u16 u = (u16)(h[e >> 1] >> ((e & 1) * 16));
                u64 m = __ballot(u != 0);
                if (m) {
                    if (u) {
                        int p = base + __popcll(m & ltmask);
                        if (p < MAXD) crow[p] = (u16)(c + lane * 8 + e);
                    }
                    base += __popcll(m);
                }
            }
        }
    }
    if (lane == 0) cnt[row] = (base < MAXD) ? base : MAXD;
}

// ---------------------------------------------------------------------------
// pooled[i,:] = (1/deg_i) * sum_k x[cols[i,k],:]  — one wave per row, ILP-4.
// Also finalizes invdeg[i]. x (4 MB) is L2-resident during this kernel.
__global__ __launch_bounds__(256) void k_gather(
    const void* __restrict__ xv, const u16* __restrict__ cols,
    const int* __restrict__ cnt, float* __restrict__ invdeg,
    float* __restrict__ pooled, const int* __restrict__ flagp)
{
    const int wave = threadIdx.x >> 6, lane = threadIdx.x & 63;
    const int row = blockIdx.x * 4 + wave;
    const int flag = *flagp;
    const u16* __restrict__ crow = cols + (size_t)row * MAXD;
    const int n = cnt[row];
    float acc = 0.f;
    int k = 0;
    if (flag) {
        const float* __restrict__ x = (const float*)xv;
        for (; k + 4 <= n; k += 4) {
            ushort4 j4 = *(const ushort4*)&crow[k];
            float v0 = x[(size_t)j4.x * HD + lane];
            float v1 = x[(size_t)j4.y * HD + lane];
            float v2 = x[(size_t)j4.z * HD + lane];
            float v3 = x[(size_t)j4.w * HD + lane];
            acc += (v0 + v1) + (v2 + v3);
        }
        for (; k < n; ++k) acc += x[(size_t)crow[k] * HD + lane];
    } else {
        const u16* __restrict__ x = (const u16*)xv;
        for (; k + 4 <= n; k += 4) {
            ushort4 j4 = *(const ushort4*)&crow[k];
            float v0 = bf2f(x[(size_t)j4.x * HD + lane]);
            float v1 = bf2f(x[(size_t)j4.y * HD + lane]);
            float v2 = bf2f(x[(size_t)j4.z * HD + lane]);
            float v3 = bf2f(x[(size_t)j4.w * HD + lane]);
            acc += (v0 + v1) + (v2 + v3);
        }
        for (; k < n; ++k) acc += bf2f(x[(size_t)crow[k] * HD + lane]);
    }
    float inv = 1.f / (float)n;                     // n >= 1 (self-loop)
    pooled[(size_t)row * HD + lane] = acc * inv;
    if (lane == 0) invdeg[row] = inv;
}

// ---------------------------------------------------------------------------
// Plain GEMM: dst[N,64] = src[N,64] @ W[64,64] + bias.
__global__ __launch_bounds__(256) void k_mm(
    const float* __restrict__ src, const void* __restrict__ W,
    const void* __restrict__ bias, float* __restrict__ dst,
    const int* __restrict__ flagp)
{
    __shared__ float Wf[64 * 64];
    __shared__ float S[4 * 64];
    const int tid = threadIdx.x;
    const int flag = *flagp;
    for (int i = tid; i < 64 * 64; i += 256) Wf[i] = ldp(W, i, flag);
    const int rbase = blockIdx.x * 4;
    S[tid] = src[(size_t)rbase * 64 + tid];
    __syncthreads();
    const int f = tid & 63, r = tid >> 6;
    float acc = ldp(bias, f, flag);
    #pragma unroll
    for (int k = 0; k < 64; ++k)
        acc = fmaf(S[r * 64 + k], Wf[k * 64 + f], acc);
    dst[(size_t)(rbase + r) * 64 + f] = acc;
}

// ---------------------------------------------------------------------------
// Column stats in f64: statsOut[f] += sum, statsOut[64+f] += sumsq.
__global__ __launch_bounds__(256) void k_stats(
    const float* __restrict__ src, double* __restrict__ statsOut)
{
    __shared__ double shs[256];
    __shared__ double shq[256];
    const int tid = threadIdx.x;
    const int f = tid & 63, rsub = tid >> 6;
    const int rbase = blockIdx.x * 64;
    double s = 0.0, q = 0.0;
    for (int r = rsub; r < 64; r += 4) {
        float v = src[(size_t)(rbase + r) * 64 + f];
        s += (double)v;
        q += (double)v * (double)v;
    }
    shs[tid] = s; shq[tid] = q;
    __syncthreads();
    if (tid < 64) {
        double S = shs[tid] + shs[64 + tid] + shs[128 + tid] + shs[192 + tid];
        double Q = shq[tid] + shq[64 + tid] + shq[128 + tid] + shq[192 + tid];
        atomicAdd(&statsOut[tid], S);
        atomicAdd(&statsOut[64 + tid], Q);
    }
}

// ---------------------------------------------------------------------------
// dst = relu(A*src + C) with A,C from f64 stats + gamma/beta. All f32 I/O.
__global__ __launch_bounds__(256) void k_bnrelu(
    const float* __restrict__ src, const double* __restrict__ stats,
    const void* __restrict__ g, const void* __restrict__ be,
    float* __restrict__ dst, const int* __restrict__ flagp)
{
    __shared__ float ac[128];
    const int tid = threadIdx.x;
    const int flag = *flagp;
    if (tid < 64) {
        double m = stats[tid] * (1.0 / N_NODES);
        double v = stats[64 + tid] * (1.0 / N_NODES) - m * m;
        float A = ldp(g, tid, flag) / sqrtf((float)v + BN_EPS);
        ac[tid] = A;
        ac[64 + tid] = ldp(be, tid, flag) - (float)m * A;
    }
    __syncthreads();
    const size_t idx = ((size_t)blockIdx.x * 256 + tid) * 4;
    const int f0 = (int)(idx & 63);
    float4 t = *(const float4*)&src[idx];
    const float4 A4 = *(const float4*)&ac[f0];
    const float4 C4 = *(const float4*)&ac[64 + f0];
    float4 r;
    r.x = fmaxf(fmaf(A4.x, t.x, C4.x), 0.f);
    r.y = fmaxf(fmaf(A4.y, t.y, C4.y), 0.f);
    r.z = fmaxf(fmaf(A4.z, t.z, C4.z), 0.f);
    r.w = fmaxf(fmaf(A4.w, t.w, C4.w), 0.f);
    *(float4*)&dst[idx] = r;
}

// ---------------------------------------------------------------------------
// pooled[i,:] = invdeg[i] * sum_k h[cols[i,k],:]  (ILP-4 gather)
__global__ __launch_bounds__(256) void k_spmm(
    const float* __restrict__ h, const u16* __restrict__ cols,
    const int* __restrict__ cnt, const float* __restrict__ invdeg,
    float* __restrict__ pooled)
{
    const int wave = threadIdx.x >> 6, lane = threadIdx.x & 63;
    const int row = blockIdx.x * 4 + wave;
    const u16* __restrict__ crow = cols + (size_t)row * MAXD;
    const int n = cnt[row];
    float acc = 0.f;
    int k = 0;
    for (; k + 4 <= n; k += 4) {
        ushort4 j4 = *(const ushort4*)&crow[k];
        float v0 = h[(size_t)j4.x * HD + lane];
        float v1 = h[(size_t)j4.y * HD + lane];
        float v2 = h[(size_t)j4.z * HD + lane];
        float v3 = h[(size_t)j4.w * HD + lane];
        acc += (v0 + v1) + (v2 + v3);
    }
    for (; k < n; ++k) acc += h[(size_t)crow[k] * HD + lane];
    pooled[(size_t)row * HD + lane] = acc * invdeg[row];
}

// ---------------------------------------------------------------------------
// out[g,:] = sum_j gp[g,j] * h[j,:]; zero weights skipped (wave-uniform test)
__global__ __launch_bounds__(1024) void k_pool(
    const void* __restrict__ gpv, const float* __restrict__ h,
    float* __restrict__ out, const int* __restrict__ flagp)
{
    __shared__ float red[16 * 64];
    const int g = blockIdx.x;
    const int wave = threadIdx.x >> 6, lane = threadIdx.x & 63;
    const int flag = *flagp;
    float acc = 0.f;
    const int jb0 = wave * (N_NODES / 16);
    if (flag) {
        const float* __restrict__ grow = (const float*)gpv + (size_t)g * N_NODES;
        for (int jb = jb0; jb < jb0 + N_NODES / 16; jb += 4) {
            float4 raw = *(const float4*)(grow + jb);
            if (raw.x != 0.f) acc += raw.x * h[(size_t)(jb + 0) * HD + lane];
            if (raw.y != 0.f) acc += raw.y * h[(size_t)(jb + 1) * HD + lane];
            if (raw.z != 0.f) acc += raw.z * h[(size_t)(jb + 2) * HD + lane];
            if (raw.w != 0.f) acc += raw.w * h[(size_t)(jb + 3) * HD + lane];
        }
    } else {
        const u16* __restrict__ grow = (const u16*)gpv + (size_t)g * N_NODES;
        for (int jb = jb0; jb < jb0 + N_NODES / 16; jb += 8) {
            uint4 raw = *(const uint4*)(grow + jb);
            const u32 w[4] = {raw.x, raw.y, raw.z, raw.w};
            #pragma unroll
            for (int e = 0; e < 8; ++e) {
                u16 u = (u16)(w[e >> 1] >> ((e & 1) * 16));
                if (u) acc += bf2f(u) * h[(size_t)(jb + e) * HD + lane];
            }
        }
    }
    red[wave * 64 + lane] = acc;
    __syncthreads();
    if (wave == 0) {
        float s = 0.f;
        #pragma unroll
        for (int w2 = 0; w2 < 16; ++w2) s += red[w2 * 64 + lane];
        out[g * 64 + lane] = s;
    }
}

// ---------------------------------------------------------------------------
extern "C" void kernel_launch(void* const* d_in, const int* in_sizes, int n_in,
                              void* d_out, int out_size, void* d_ws, size_t ws_size,
                              hipStream_t stream)
{
    const void* x    = d_in[0];
    const void* adj  = d_in[1];
    const void* gp   = d_in[2];
    const void* W1_0 = d_in[3];
    const void* b1_0 = d_in[4];
    const void* g1_0 = d_in[5];
    const void* be1_0= d_in[6];
    const void* W2_0 = d_in[7];
    const void* b2_0 = d_in[8];
    const void* g_0  = d_in[9];
    const void* be_0 = d_in[10];
    const void* W1_1 = d_in[11];
    const void* b1_1 = d_in[12];
    const void* g1_1 = d_in[13];
    const void* be1_1= d_in[14];
    const void* W2_1 = d_in[15];
    const void* b2_1 = d_in[16];
    const void* g_1  = d_in[17];
    const void* be_1 = d_in[18];

    char* ws = (char*)d_ws;
    float*  P      = (float*) (ws);                        // 4 MB
    float*  A      = (float*) (ws + (4u  << 20));          // 4 MB
    float*  B      = (float*) (ws + (8u  << 20));          // 4 MB
    u16*    cols   = (u16*)   (ws + (12u << 20));          // 6 MB
    int*    cnt    = (int*)   (ws + (18u << 20));          // 64 KB
    float*  invdeg = (float*) (ws + (18u << 20) + 65536);  // 64 KB
    double* sd     = (double*)(ws + (18u << 20) + 131072); // 512 f64 = 4 KB
    int*    flag   = (int*)   (ws + (18u << 20) + 131072 + 4096);

    // Outputs are float32 (reference output dtype). Output 1 (h_nodes) is
    // written in-place by the final k_bnrelu; k_pool reads it from d_out.
    float* out_pool  = (float*)d_out;            // [128,64]
    float* out_nodes = (float*)d_out + GG * HD;  // [16384,64]

    const int EB = (N_NODES * HD / 4) / 256;  // elementwise grid (1024)

    k_init<<<2, 256, 0, stream>>>((const u32*)adj, sd, flag);
    k_scan<<<N_NODES / 4, 256, 0, stream>>>(adj, cols, cnt, flag);
    k_gather<<<N_NODES / 4, 256, 0, stream>>>(x, cols, cnt, invdeg, P, flag);

    // ----- layer 0 -----
    k_mm<<<N_NODES / 4, 256, 0, stream>>>(P, W1_0, b1_0, A, flag);
    k_stats<<<256, 256, 0, stream>>>(A, sd + 0);
    k_bnrelu<<<EB, 256, 0, stream>>>(A, sd + 0, g1_0, be1_0, B, flag);
    k_mm<<<N_NODES / 4, 256, 0, stream>>>(B, W2_0, b2_0, P, flag);
    k_stats<<<256, 256, 0, stream>>>(P, sd + 128);
    k_bnrelu<<<EB, 256, 0, stream>>>(P, sd + 128, g_0, be_0, A, flag);   // h0
    k_spmm<<<N_NODES / 4, 256, 0, stream>>>(A, cols, cnt, invdeg, B);    // pooled1
    // ----- layer 1 -----
    k_mm<<<N_NODES / 4, 256, 0, stream>>>(B, W1_1, b1_1, P, flag);
    k_stats<<<256, 256, 0, stream>>>(P, sd + 256);
    k_bnrelu<<<EB, 256, 0, stream>>>(P, sd + 256, g1_1, be1_1, A, flag);
    k_mm<<<N_NODES / 4, 256, 0, stream>>>(A, W2_1, b2_1, B, flag);
    k_stats<<<256, 256, 0, stream>>>(B, sd + 384);
    k_bnrelu<<<EB, 256, 0, stream>>>(B, sd + 384, g_1, be_1, out_nodes, flag); // h1 -> output 1
    k_pool<<<GG, 1024, 0, stream>>>(gp, out_nodes, out_pool, flag);            // output 0
}

// Round 8
// 1634.447 us; speedup vs baseline: 1.0876x; 1.0232x over previous
//
#include <hip/hip_runtime.h>
#include <hip/hip_bf16.h>
#include <stdint.h>

#define N_NODES 16384
#define GG      128
#define HD      64
#define MAXD    192
#define BN_EPS  1e-5f

typedef unsigned short u16;
typedef unsigned int   u32;
typedef unsigned long long u64;
typedef u32 u32x4 __attribute__((ext_vector_type(4)));  // nontemporal-compatible

__device__ __forceinline__ float bf2f(u16 u) {
    union { u32 i; float f; } c; c.i = ((u32)u) << 16; return c.f;
}
// param load in native dtype (flag: 1=f32, 0=bf16)
__device__ __forceinline__ float ldp(const void* p, int i, int flag) {
    return flag ? ((const float*)p)[i] : bf2f(((const u16*)p)[i]);
}

// ---------------------------------------------------------------------------
// zero f64 stats (512) + probe input dtype from adj[0][0]==1.0:
// f32 -> word0 low16 == 0; bf16 -> low16 = 0x3F80 != 0.
__global__ __launch_bounds__(256) void k_init(
    const u32* __restrict__ adj32, double* __restrict__ statsD,
    int* __restrict__ flag)
{
    const int gid = blockIdx.x * 256 + threadIdx.x;
    if (gid < 512) statsD[gid] = 0.0;
    if (gid == 0) *flag = ((adj32[0] & 0xFFFFu) == 0) ? 1 : 0;
}

// ---------------------------------------------------------------------------
// Streaming CSR build, no atomics: one wave per row, ballot + popcount-prefix
// compaction. 2-deep prefetch (2 outstanding 1 KiB loads/wave) and
// NON-TEMPORAL adj loads so the 1 GiB stream doesn't evict cols/x from L2.
__global__ __launch_bounds__(256) void k_scan(
    const void* __restrict__ adjv, u16* __restrict__ cols,
    int* __restrict__ cnt, const int* __restrict__ flagp)
{
    const int wave = threadIdx.x >> 6, lane = threadIdx.x & 63;
    const int row = blockIdx.x * 4 + wave;
    u16* __restrict__ crow = cols + (size_t)row * MAXD;
    const int flag = *flagp;
    const u64 ltmask = ((1ull << lane) - 1ull);

    int base = 0;
    if (flag) {  // ---- f32: u32x4 = 4 elements, 256 elems/wave-chunk ----
        const u32x4* __restrict__ arow =
            (const u32x4*)((const u32*)adjv + (size_t)row * N_NODES) + lane;
        u32x4 p0 = __builtin_nontemporal_load(arow);
        u32x4 p1 = __builtin_nontemporal_load(arow + 64);
        for (int c = 0; c < N_NODES; c += 256) {
            u32x4 raw = p0;
            p0 = p1;
            if (c + 512 < N_NODES)
                p1 = __builtin_nontemporal_load(arow + (c + 512) / 4);
            #pragma unroll
            for (int e = 0; e < 4; ++e) {
                u32 w = raw[e];
                u64 m = __ballot(w != 0);
                if (m) {
                    if (w) {
                        int p = base + __popcll(m & ltmask);
                        if (p < MAXD) crow[p] = (u16)(c + lane * 4 + e);
                    }
                    base += __popcll(m);
                }
            }
        }
    } else {     // ---- bf16: u32x4 = 8 elements, 512 elems/wave-chunk ----
        const u32x4* __restrict__ arow =
            (const u32x4*)((const u16*)adjv + (size_t)row * N_NODES) + lane;
        u32x4 p0 = __builtin_nontemporal_load(arow);
        u32x4 p1 = __builtin_nontemporal_load(arow + 64);
        for (int c = 0; c < N_NODES; c += 512) {
            u32x4 raw = p0;
            p0 = p1;
            if (c + 1024 < N_NODES)
                p1 = __builtin_nontemporal_load(arow + (c + 1024) / 8);
            #pragma unroll
            for (int e = 0; e < 8; ++e) {
                u16 u = (u16)(raw[e >> 1] >> ((e & 1) * 16));
                u64 m = __ballot(u != 0);
                if (m) {
                    if (u) {
                        int p = base + __popcll(m & ltmask);
                        if (p < MAXD) crow[p] = (u16)(c + lane * 8 + e);
                    }
                    base += __popcll(m);
                }
            }
        }
    }
    if (lane == 0) cnt[row] = (base < MAXD) ? base : MAXD;
}

// ---------------------------------------------------------------------------
// pooled[i,:] = (1/deg_i) * sum_k x[cols[i,k],:]  — one wave per row, ILP-4.
__global__ __launch_bounds__(256) void k_gather(
    const void* __restrict__ xv, const u16* __restrict__ cols,
    const int* __restrict__ cnt, float* __restrict__ invdeg,
    float* __restrict__ pooled, const int* __restrict__ flagp)
{
    const int wave = threadIdx.x >> 6, lane = threadIdx.x & 63;
    const int row = blockIdx.x * 4 + wave;
    const int flag = *flagp;
    const u16* __restrict__ crow = cols + (size_t)row * MAXD;
    const int n = cnt[row];
    float acc = 0.f;
    int k = 0;
    if (flag) {
        const float* __restrict__ x = (const float*)xv;
        for (; k + 4 <= n; k += 4) {
            ushort4 j4 = *(const ushort4*)&crow[k];
            float v0 = x[(size_t)j4.x * HD + lane];
            float v1 = x[(size_t)j4.y * HD + lane];
            float v2 = x[(size_t)j4.z * HD + lane];
            float v3 = x[(size_t)j4.w * HD + lane];
            acc += (v0 + v1) + (v2 + v3);
        }
        for (; k < n; ++k) acc += x[(size_t)crow[k] * HD + lane];
    } else {
        const u16* __restrict__ x = (const u16*)xv;
        for (; k + 4 <= n; k += 4) {
            ushort4 j4 = *(const ushort4*)&crow[k];
            float v0 = bf2f(x[(size_t)j4.x * HD + lane]);
            float v1 = bf2f(x[(size_t)j4.y * HD + lane]);
            float v2 = bf2f(x[(size_t)j4.z * HD + lane]);
            float v3 = bf2f(x[(size_t)j4.w * HD + lane]);
            acc += (v0 + v1) + (v2 + v3);
        }
        for (; k < n; ++k) acc += bf2f(x[(size_t)crow[k] * HD + lane]);
    }
    float inv = 1.f / (float)n;                     // n >= 1 (self-loop)
    pooled[(size_t)row * HD + lane] = acc * inv;
    if (lane == 0) invdeg[row] = inv;
}

// ---------------------------------------------------------------------------
// dst[N,64] = f(src)[N,64] @ W[64,64] + bias.
// f = identity (AFFINE=false) or per-feature relu(A*v+C) (AFFINE=true),
// applied once per LDS element at stage-in (2 VALU/elt).
template<bool AFFINE>
__global__ __launch_bounds__(256) void k_mm(
    const float* __restrict__ src, const double* __restrict__ stats,
    const void* __restrict__ g, const void* __restrict__ be,
    const void* __restrict__ W, const void* __restrict__ bias,
    float* __restrict__ dst, const int* __restrict__ flagp)
{
    __shared__ float Wf[64 * 64];
    __shared__ float S[4 * 64];
    __shared__ float ac[128];
    const int tid = threadIdx.x;
    const int flag = *flagp;
    if (AFFINE) {
        if (tid < 64) {
            double m = stats[tid] * (1.0 / N_NODES);
            double v = stats[64 + tid] * (1.0 / N_NODES) - m * m;
            float A = ldp(g, tid, flag) / sqrtf((float)v + BN_EPS);
            ac[tid] = A;
            ac[64 + tid] = ldp(be, tid, flag) - (float)m * A;
        }
        __syncthreads();
    }
    for (int i = tid; i < 64 * 64; i += 256) Wf[i] = ldp(W, i, flag);
    const int rbase = blockIdx.x * 4;
    {
        float v = src[(size_t)rbase * 64 + tid];
        if (AFFINE) v = fmaxf(fmaf(ac[tid & 63], v, ac[64 + (tid & 63)]), 0.f);
        S[tid] = v;
    }
    __syncthreads();
    const int f = tid & 63, r = tid >> 6;
    float acc = ldp(bias, f, flag);
    #pragma unroll
    for (int k = 0; k < 64; ++k)
        acc = fmaf(S[r * 64 + k], Wf[k * 64 + f], acc);
    dst[(size_t)(rbase + r) * 64 + f] = acc;
}

// ---------------------------------------------------------------------------
// Column stats in f64: statsOut[f] += sum, statsOut[64+f] += sumsq.
// 256 blocks -> 256 serial RMWs/address (proven cheap; do NOT widen grid).
__global__ __launch_bounds__(256) void k_stats(
    const float* __restrict__ src, double* __restrict__ statsOut)
{
    __shared__ double shs[256];
    __shared__ double shq[256];
    const int tid = threadIdx.x;
    const int f = tid & 63, rsub = tid >> 6;
    const int rbase = blockIdx.x * 64;
    double s = 0.0, q = 0.0;
    for (int r = rsub; r < 64; r += 4) {
        float v = src[(size_t)(rbase + r) * 64 + f];
        s += (double)v;
        q += (double)v * (double)v;
    }
    shs[tid] = s; shq[tid] = q;
    __syncthreads();
    if (tid < 64) {
        double S = shs[tid] + shs[64 + tid] + shs[128 + tid] + shs[192 + tid];
        double Q = shq[tid] + shq[64 + tid] + shq[128 + tid] + shq[192 + tid];
        atomicAdd(&statsOut[tid], S);
        atomicAdd(&statsOut[64 + tid], Q);
    }
}

// ---------------------------------------------------------------------------
// dst = relu(A*src + C) (final h1 -> output 1)
__global__ __launch_bounds__(256) void k_bnrelu(
    const float* __restrict__ src, const double* __restrict__ stats,
    const void* __restrict__ g, const void* __restrict__ be,
    float* __restrict__ dst, const int* __restrict__ flagp)
{
    __shared__ float ac[128];
    const int tid = threadIdx.x;
    const int flag = *flagp;
    if (tid < 64) {
        double m = stats[tid] * (1.0 / N_NODES);
        double v = stats[64 + tid] * (1.0 / N_NODES) - m * m;
        float A = ldp(g, tid, flag) / sqrtf((float)v + BN_EPS);
        ac[tid] = A;
        ac[64 + tid] = ldp(be, tid, flag) - (float)m * A;
    }
    __syncthreads();
    const size_t idx = ((size_t)blockIdx.x * 256 + tid) * 4;
    const int f0 = (int)(idx & 63);
    float4 t = *(const float4*)&src[idx];
    const float4 A4 = *(const float4*)&ac[f0];
    const float4 C4 = *(const float4*)&ac[64 + f0];
    float4 r;
    r.x = fmaxf(fmaf(A4.x, t.x, C4.x), 0.f);
    r.y = fmaxf(fmaf(A4.y, t.y, C4.y), 0.f);
    r.z = fmaxf(fmaf(A4.z, t.z, C4.z), 0.f);
    r.w = fmaxf(fmaf(A4.w, t.w, C4.w), 0.f);
    *(float4*)&dst[idx] = r;
}

// ---------------------------------------------------------------------------
// pooled[i,:] = invdeg[i] * sum_k relu(A*t[cols[i,k],:]+C)
// (layer-0 outer BN+relu fused into the layer-1 aggregation gather)
__global__ __launch_bounds__(256) void k_spmm(
    const float* __restrict__ t, const double* __restrict__ stats,
    const void* __restrict__ g, const void* __restrict__ be,
    const u16* __restrict__ cols, const int* __restrict__ cnt,
    const float* __restrict__ invdeg, float* __restrict__ pooled,
    const int* __restrict__ flagp)
{
    const int wave = threadIdx.x >> 6, lane = threadIdx.x & 63;
    const int row = blockIdx.x * 4 + wave;
    const int flag = *flagp;
    double md = stats[lane] * (1.0 / N_NODES);
    double vd = stats[64 + lane] * (1.0 / N_NODES) - md * md;
    const float A = ldp(g, lane, flag) / sqrtf((float)vd + BN_EPS);
    const float C = ldp(be, lane, flag) - (float)md * A;

    const u16* __restrict__ crow = cols + (size_t)row * MAXD;
    const int n = cnt[row];
    float acc = 0.f;
    int k = 0;
    for (; k + 4 <= n; k += 4) {
        ushort4 j4 = *(const ushort4*)&crow[k];
        float v0 = t[(size_t)j4.x * HD + lane];
        float v1 = t[(size_t)j4.y * HD + lane];
        float v2 = t[(size_t)j4.z * HD + lane];
        float v3 = t[(size_t)j4.w * HD + lane];
        acc += fmaxf(fmaf(A, v0, C), 0.f);
        acc += fmaxf(fmaf(A, v1, C), 0.f);
        acc += fmaxf(fmaf(A, v2, C), 0.f);
        acc += fmaxf(fmaf(A, v3, C), 0.f);
    }
    for (; k < n; ++k) {
        float vv = t[(size_t)crow[k] * HD + lane];
        acc += fmaxf(fmaf(A, vv, C), 0.f);
    }
    pooled[(size_t)row * HD + lane] = acc * invdeg[row];
}

// ---------------------------------------------------------------------------
// out[g,:] = sum_j gp[g,j] * h[j,:]; zero weights skipped (wave-uniform test)
__global__ __launch_bounds__(1024) void k_pool(
    const void* __restrict__ gpv, const float* __restrict__ h,
    float* __restrict__ out, const int* __restrict__ flagp)
{
    __shared__ float red[16 * 64];
    const int g = blockIdx.x;
    const int wave = threadIdx.x >> 6, lane = threadIdx.x & 63;
    const int flag = *flagp;
    float acc = 0.f;
    const int jb0 = wave * (N_NODES / 16);
    if (flag) {
        const float* __restrict__ grow = (const float*)gpv + (size_t)g * N_NODES;
        for (int jb = jb0; jb < jb0 + N_NODES / 16; jb += 4) {
            float4 raw = *(const float4*)(grow + jb);
            if (raw.x != 0.f) acc += raw.x * h[(size_t)(jb + 0) * HD + lane];
            if (raw.y != 0.f) acc += raw.y * h[(size_t)(jb + 1) * HD + lane];
            if (raw.z != 0.f) acc += raw.z * h[(size_t)(jb + 2) * HD + lane];
            if (raw.w != 0.f) acc += raw.w * h[(size_t)(jb + 3) * HD + lane];
        }
    } else {
        const u16* __restrict__ grow = (const u16*)gpv + (size_t)g * N_NODES;
        for (int jb = jb0; jb < jb0 + N_NODES / 16; jb += 8) {
            uint4 raw = *(const uint4*)(grow + jb);
            const u32 w[4] = {raw.x, raw.y, raw.z, raw.w};
            #pragma unroll
            for (int e = 0; e < 8; ++e) {
                u16 u = (u16)(w[e >> 1] >> ((e & 1) * 16));
                if (u) acc += bf2f(u) * h[(size_t)(jb + e) * HD + lane];
            }
        }
    }
    red[wave * 64 + lane] = acc;
    __syncthreads();
    if (wave == 0) {
        float s = 0.f;
        #pragma unroll
        for (int w2 = 0; w2 < 16; ++w2) s += red[w2 * 64 + lane];
        out[g * 64 + lane] = s;
    }
}

// ---------------------------------------------------------------------------
extern "C" void kernel_launch(void* const* d_in, const int* in_sizes, int n_in,
                              void* d_out, int out_size, void* d_ws, size_t ws_size,
                              hipStream_t stream)
{
    const void* x    = d_in[0];
    const void* adj  = d_in[1];
    const void* gp   = d_in[2];
    const void* W1_0 = d_in[3];
    const void* b1_0 = d_in[4];
    const void* g1_0 = d_in[5];
    const void* be1_0= d_in[6];
    const void* W2_0 = d_in[7];
    const void* b2_0 = d_in[8];
    const void* g_0  = d_in[9];
    const void* be_0 = d_in[10];
    const void* W1_1 = d_in[11];
    const void* b1_1 = d_in[12];
    const void* g1_1 = d_in[13];
    const void* be1_1= d_in[14];
    const void* W2_1 = d_in[15];
    const void* b2_1 = d_in[16];
    const void* g_1  = d_in[17];
    const void* be_1 = d_in[18];

    char* ws = (char*)d_ws;
    float*  P      = (float*) (ws);                        // 4 MB
    float*  A      = (float*) (ws + (4u  << 20));          // 4 MB
    float*  B      = (float*) (ws + (8u  << 20));          // 4 MB
    u16*    cols   = (u16*)   (ws + (12u << 20));          // 6 MB
    int*    cnt    = (int*)   (ws + (18u << 20));          // 64 KB
    float*  invdeg = (float*) (ws + (18u << 20) + 65536);  // 64 KB
    double* sd     = (double*)(ws + (18u << 20) + 131072); // 512 f64
    int*    flag   = (int*)   (ws + (18u << 20) + 131072 + 4096);

    // Outputs are float32. Output 1 (h_nodes) written by final k_bnrelu;
    // k_pool reads it from d_out.
    float* out_pool  = (float*)d_out;            // [128,64]
    float* out_nodes = (float*)d_out + GG * HD;  // [16384,64]

    const int EB = (N_NODES * HD / 4) / 256;  // elementwise grid (1024)

    k_init<<<2, 256, 0, stream>>>((const u32*)adj, sd, flag);
    k_scan<<<N_NODES / 4, 256, 0, stream>>>(adj, cols, cnt, flag);
    k_gather<<<N_NODES / 4, 256, 0, stream>>>(x, cols, cnt, invdeg, P, flag);

    // ----- layer 0 -----
    k_mm<false><<<N_NODES / 4, 256, 0, stream>>>(P, nullptr, nullptr, nullptr,
                                                 W1_0, b1_0, A, flag);
    k_stats<<<256, 256, 0, stream>>>(A, sd + 0);
    k_mm<true><<<N_NODES / 4, 256, 0, stream>>>(A, sd + 0, g1_0, be1_0,
                                                W2_0, b2_0, P, flag);
    k_stats<<<256, 256, 0, stream>>>(P, sd + 128);
    // layer-0 outer BN+relu fused into the layer-1 aggregation gather:
    k_spmm<<<N_NODES / 4, 256, 0, stream>>>(P, sd + 128, g_0, be_0,
                                            cols, cnt, invdeg, B, flag);
    // ----- layer 1 -----
    k_mm<false><<<N_NODES / 4, 256, 0, stream>>>(B, nullptr, nullptr, nullptr,
                                                 W1_1, b1_1, A, flag);
    k_stats<<<256, 256, 0, stream>>>(A, sd + 256);
    k_mm<true><<<N_NODES / 4, 256, 0, stream>>>(A, sd + 256, g1_1, be1_1,
                                                W2_1, b2_1, P, flag);
    k_stats<<<256, 256, 0, stream>>>(P, sd + 384);
    k_bnrelu<<<EB, 256, 0, stream>>>(P, sd + 384, g_1, be_1, out_nodes, flag);
    k_pool<<<GG, 1024, 0, stream>>>(gp, out_nodes, out_pool, flag);
}